// Round 1
// baseline (3321.060 us; speedup 1.0000x reference)
//
#include <hip/hip_runtime.h>
#include <hip/hip_bf16.h>

// SetMatchingModel: S=48 sets, N=80 items, D=128, H=2 heads, HS=128.
// Key structure: encoder output is pair-independent (per-set), and the final
// score matrix is symmetric -> only 1176 unordered pairs computed.

#define SS 48
#define NI 80
#define DD 128
#define TPB 320

__device__ __forceinline__ float gelu_f(float x){
  return 0.5f * x * (1.0f + erff(x * 0.7071067811865475f));
}

// ---------------- generic tiled fp32 GEMM: C = act(A[M,K] @ B[K,N]) --------
template<int GELU>
__global__ __launch_bounds__(256) void gemm_k(const float* __restrict__ A,
                                              const float* __restrict__ B,
                                              float* __restrict__ C,
                                              int M, int Nn, int K)
{
  __shared__ __align__(16) float As[64*20];
  __shared__ __align__(16) float Bs[16*68];
  const int t = threadIdx.x;
  const int tx = t & 15, ty = t >> 4;
  const int bx = blockIdx.x, by = blockIdx.y;
  float acc[4][4] = {};
  for (int k0 = 0; k0 < K; k0 += 16) {
    {
      int idx = t * 4;
      int r = idx >> 4, c = idx & 15;
      *(float4*)&As[r*20 + c] =
          *(const float4*)&A[(size_t)(by*64 + r)*K + k0 + c];
      int kk = idx >> 6, col = idx & 63;
      *(float4*)&Bs[kk*68 + col] =
          *(const float4*)&B[(size_t)(k0 + kk)*Nn + bx*64 + col];
    }
    __syncthreads();
#pragma unroll
    for (int k2 = 0; k2 < 16; ++k2) {
      float ar[4], br[4];
#pragma unroll
      for (int i2 = 0; i2 < 4; ++i2) ar[i2] = As[(ty*4+i2)*20 + k2];
#pragma unroll
      for (int j2 = 0; j2 < 4; ++j2) br[j2] = Bs[k2*68 + tx*4 + j2];
#pragma unroll
      for (int i2 = 0; i2 < 4; ++i2)
#pragma unroll
        for (int j2 = 0; j2 < 4; ++j2)
          acc[i2][j2] = fmaf(ar[i2], br[j2], acc[i2][j2]);
    }
    __syncthreads();
  }
#pragma unroll
  for (int i2 = 0; i2 < 4; ++i2) {
    float4 o4;
    float* po = (float*)&o4;
#pragma unroll
    for (int j2 = 0; j2 < 4; ++j2)
      po[j2] = GELU ? gelu_f(acc[i2][j2]) : acc[i2][j2];
    *(float4*)&C[(size_t)(by*64 + ty*4 + i2)*Nn + bx*64 + tx*4] = o4;
  }
}

// ---------------- per-row item layer norm (rows of 128), zero kept-out rows -
__global__ __launch_bounds__(64) void norm_k(const float* __restrict__ in,
                                             float* __restrict__ out)
{
  const int r = blockIdx.x, t = threadIdx.x;
  float v0 = in[(size_t)r*DD + t];
  float v1 = in[(size_t)r*DD + t + 64];
  float sm = v0 + v1;
#pragma unroll
  for (int off = 1; off < 64; off <<= 1) sm += __shfl_xor(sm, off, 64);
  float mean = sm * (1.0f/128.0f);
  float d0 = v0 - mean, d1 = v1 - mean;
  float vs = d0*d0 + d1*d1;
#pragma unroll
  for (int off = 1; off < 64; off <<= 1) vs += __shfl_xor(vs, off, 64);
  float stdv = sqrtf(vs * (1.0f/128.0f));
  float inv = 1.0f / (stdv + 1e-3f);
  bool keep = (sm != 0.0f);
  out[(size_t)r*DD + t]      = keep ? d0*inv : 0.0f;
  out[(size_t)r*DD + t + 64] = keep ? d1*inv : 0.0f;
}

// ---------------- fused attention phase -------------------------------------
// For ordered (a,b): x4 = base[a] + MHA(Q[a],K[b],V[b]) @ Wh ; z = norm(x4);
// x4 += gelu(z @ Wfc).  Result left in regs x4[4][8].
// Thread map (320 thr): rg=t>>4 (0..19), cg=t&15; rows r=rg+20u (u<4),
// cols c=cg*8+w (w<8); score cols m=cg+16v (v<5).
// scr: NI*DD bf16 scratch (probs A[80][80] -> O[80][128] -> z[80][128]).
// tiles: >=3200 floats.
__device__ void attn_phase(int a, int b, int t,
    const float* __restrict__ Qg, const float* __restrict__ Kg,
    const float* __restrict__ Vg, const float* __restrict__ baseg,
    const float* __restrict__ Whg, const float* __restrict__ Wfcg,
    __hip_bfloat16* __restrict__ scr, float* __restrict__ tiles,
    float x4[4][8])
{
  const int rg = t >> 4;
  const int cg = t & 15;
  const int c0 = cg * 8;
  const float isq = 0.08838834764831845f; // 1/sqrt(128)
#pragma unroll
  for (int u = 0; u < 4; ++u)
#pragma unroll
    for (int w = 0; w < 8; ++w) x4[u][w] = 0.0f;

  for (int h = 0; h < 2; ++h) {
    // ---- scores s = Q K^T / sqrt(HS), regs 4x5 per thread ----
    float s[4][5] = {};
    float* Qt = tiles;          // [80][20]
    float* Kt = tiles + 1600;   // [80][20]
    for (int dc = 0; dc < 8; ++dc) {
      {
        int idx = t * 4;
        int n = idx >> 4, c = idx & 15;
        *(float4*)&Qt[n*20 + c] =
          *(const float4*)&Qg[(size_t)(a*NI + n)*256 + h*128 + dc*16 + c];
        *(float4*)&Kt[n*20 + c] =
          *(const float4*)&Kg[(size_t)(b*NI + n)*256 + h*128 + dc*16 + c];
      }
      __syncthreads();
#pragma unroll
      for (int k2 = 0; k2 < 16; ++k2) {
        float qv[4], kv[5];
#pragma unroll
        for (int u = 0; u < 4; ++u) qv[u] = Qt[(rg + 20*u)*20 + k2];
#pragma unroll
        for (int v = 0; v < 5; ++v) kv[v] = Kt[(cg + 16*v)*20 + k2];
#pragma unroll
        for (int u = 0; u < 4; ++u)
#pragma unroll
          for (int v = 0; v < 5; ++v)
            s[u][v] = fmaf(qv[u], kv[v], s[u][v]);
      }
      __syncthreads();
    }
#pragma unroll
    for (int u = 0; u < 4; ++u)
#pragma unroll
      for (int v = 0; v < 5; ++v) s[u][v] *= isq;

    // ---- masked softmax (mask: s != 0; max over raw row incl. zeros) ----
    __hip_bfloat16* Abuf = scr; // [80][80] probs
#pragma unroll
    for (int u = 0; u < 4; ++u) {
      float mx = s[u][0];
#pragma unroll
      for (int v = 1; v < 5; ++v) mx = fmaxf(mx, s[u][v]);
#pragma unroll
      for (int off = 1; off < 16; off <<= 1) mx = fmaxf(mx, __shfl_xor(mx, off, 64));
      float ev[5]; float sum = 0.0f;
#pragma unroll
      for (int v = 0; v < 5; ++v) {
        float sv = s[u][v];
        float e = (sv != 0.0f) ? expf(sv - mx) : 0.0f;
        ev[v] = e; sum += e;
      }
#pragma unroll
      for (int off = 1; off < 16; off <<= 1) sum += __shfl_xor(sum, off, 64);
      float inv = 1.0f / (sum + 1e-10f);
#pragma unroll
      for (int v = 0; v < 5; ++v)
        Abuf[(rg + 20*u)*80 + cg + 16*v] = __float2bfloat16(ev[v] * inv);
    }
    __syncthreads();

    // ---- O = A @ V (per head), accum in regs ----
    float o[4][8] = {};
    float* Vt = tiles; // [16][128]
    for (int mc = 0; mc < 5; ++mc) {
      for (int idx = t; idx < 2048; idx += TPB) {
        int mm = idx >> 7, c = idx & 127;
        Vt[idx] = Vg[(size_t)(b*NI + mc*16 + mm)*256 + h*128 + c];
      }
      __syncthreads();
#pragma unroll
      for (int mm = 0; mm < 16; ++mm) {
        float av[4];
#pragma unroll
        for (int u = 0; u < 4; ++u)
          av[u] = __bfloat162float(Abuf[(rg + 20*u)*80 + mc*16 + mm]);
        float4 va = *(float4*)&Vt[mm*128 + c0];
        float4 vb = *(float4*)&Vt[mm*128 + c0 + 4];
        float vv[8] = {va.x,va.y,va.z,va.w,vb.x,vb.y,vb.z,vb.w};
#pragma unroll
        for (int u = 0; u < 4; ++u)
#pragma unroll
          for (int w = 0; w < 8; ++w)
            o[u][w] = fmaf(av[u], vv[w], o[u][w]);
      }
      __syncthreads();
    }
    // stash O (bf16) in scr (probs dead now)
#pragma unroll
    for (int u = 0; u < 4; ++u)
#pragma unroll
      for (int w = 0; w < 8; ++w)
        scr[(rg + 20*u)*DD + c0 + w] = __float2bfloat16(o[u][w]);
    __syncthreads();

    // ---- x4 += O @ Wh[h*128: (h+1)*128, :] ----
    for (int dc = 0; dc < 8; ++dc) {
      float* Wt = tiles; // [16][128]
      for (int idx = t; idx < 2048; idx += TPB) {
        int d2 = idx >> 7, c = idx & 127;
        Wt[idx] = Whg[(size_t)(h*128 + dc*16 + d2)*DD + c];
      }
      __syncthreads();
#pragma unroll
      for (int d2 = 0; d2 < 16; ++d2) {
        float ov[4];
#pragma unroll
        for (int u = 0; u < 4; ++u)
          ov[u] = __bfloat162float(scr[(rg + 20*u)*DD + dc*16 + d2]);
        float4 wa = *(float4*)&Wt[d2*128 + c0];
        float4 wb = *(float4*)&Wt[d2*128 + c0 + 4];
        float wv[8] = {wa.x,wa.y,wa.z,wa.w,wb.x,wb.y,wb.z,wb.w};
#pragma unroll
        for (int u = 0; u < 4; ++u)
#pragma unroll
          for (int w = 0; w < 8; ++w)
            x4[u][w] = fmaf(ov[u], wv[w], x4[u][w]);
      }
      __syncthreads();
    }
  } // heads

  // ---- residual: x4 += base[a] ----
#pragma unroll
  for (int u = 0; u < 4; ++u) {
    float4 ba = *(const float4*)&baseg[(size_t)(a*NI + rg + 20*u)*DD + c0];
    float4 bb = *(const float4*)&baseg[(size_t)(a*NI + rg + 20*u)*DD + c0 + 4];
    x4[u][0] += ba.x; x4[u][1] += ba.y; x4[u][2] += ba.z; x4[u][3] += ba.w;
    x4[u][4] += bb.x; x4[u][5] += bb.y; x4[u][6] += bb.z; x4[u][7] += bb.w;
  }

  // ---- z = item_norm(x4) -> scr (bf16) ----
#pragma unroll
  for (int u = 0; u < 4; ++u) {
    float sm = 0.0f;
#pragma unroll
    for (int w = 0; w < 8; ++w) sm += x4[u][w];
#pragma unroll
    for (int off = 1; off < 16; off <<= 1) sm += __shfl_xor(sm, off, 64);
    float mean = sm * (1.0f/128.0f);
    float vs = 0.0f;
#pragma unroll
    for (int w = 0; w < 8; ++w) { float d = x4[u][w] - mean; vs = fmaf(d, d, vs); }
#pragma unroll
    for (int off = 1; off < 16; off <<= 1) vs += __shfl_xor(vs, off, 64);
    float stdv = sqrtf(vs * (1.0f/128.0f));
    float inv = 1.0f / (stdv + 1e-3f);
    bool keep = (sm != 0.0f);
#pragma unroll
    for (int w = 0; w < 8; ++w) {
      float zv = keep ? (x4[u][w] - mean) * inv : 0.0f;
      scr[(rg + 20*u)*DD + c0 + w] = __float2bfloat16(zv);
    }
  }
  __syncthreads();

  // ---- x4 += gelu(z @ Wfc) ----
  float tacc[4][8] = {};
  for (int dc = 0; dc < 8; ++dc) {
    float* Wt = tiles;
    for (int idx = t; idx < 2048; idx += TPB) {
      int d2 = idx >> 7, c = idx & 127;
      Wt[idx] = Wfcg[(size_t)(dc*16 + d2)*DD + c];
    }
    __syncthreads();
#pragma unroll
    for (int d2 = 0; d2 < 16; ++d2) {
      float zv[4];
#pragma unroll
      for (int u = 0; u < 4; ++u)
        zv[u] = __bfloat162float(scr[(rg + 20*u)*DD + dc*16 + d2]);
      float4 wa = *(float4*)&Wt[d2*128 + c0];
      float4 wb = *(float4*)&Wt[d2*128 + c0 + 4];
      float wv[8] = {wa.x,wa.y,wa.z,wa.w,wb.x,wb.y,wb.z,wb.w};
#pragma unroll
      for (int u = 0; u < 4; ++u)
#pragma unroll
        for (int w = 0; w < 8; ++w)
          tacc[u][w] = fmaf(zv[u], wv[w], tacc[u][w]);
    }
    __syncthreads();
  }
#pragma unroll
  for (int u = 0; u < 4; ++u)
#pragma unroll
    for (int w = 0; w < 8; ++w)
      x4[u][w] += gelu_f(tacc[u][w]);
}

// ---------------- encoder: per-set self-attention block ---------------------
__global__ __launch_bounds__(TPB) void encoder_k(
    const float* __restrict__ Qg, const float* __restrict__ Kg,
    const float* __restrict__ Vg, const float* __restrict__ hg,
    const float* __restrict__ Whg, const float* __restrict__ Wfcg,
    float* __restrict__ e2g, float* __restrict__ z3g)
{
  __shared__ __align__(16) __hip_bfloat16 scr[NI*DD];
  __shared__ __align__(16) float tiles[3200];
  const int i = blockIdx.x;
  const int t = threadIdx.x;
  const int rg = t >> 4, cg = t & 15, c0 = cg*8;
  float x4[4][8];
  attn_phase(i, i, t, Qg, Kg, Vg, hg, Whg, Wfcg, scr, tiles, x4);
#pragma unroll
  for (int u = 0; u < 4; ++u) {
    float4 oa = {x4[u][0],x4[u][1],x4[u][2],x4[u][3]};
    float4 ob = {x4[u][4],x4[u][5],x4[u][6],x4[u][7]};
    *(float4*)&e2g[(size_t)(i*NI + rg + 20*u)*DD + c0]     = oa;
    *(float4*)&e2g[(size_t)(i*NI + rg + 20*u)*DD + c0 + 4] = ob;
    // z3 = item_norm(e2)
    float sm = 0.0f;
#pragma unroll
    for (int w = 0; w < 8; ++w) sm += x4[u][w];
#pragma unroll
    for (int off = 1; off < 16; off <<= 1) sm += __shfl_xor(sm, off, 64);
    float mean = sm * (1.0f/128.0f);
    float vs = 0.0f;
#pragma unroll
    for (int w = 0; w < 8; ++w) { float d = x4[u][w] - mean; vs = fmaf(d, d, vs); }
#pragma unroll
    for (int off = 1; off < 16; off <<= 1) vs += __shfl_xor(vs, off, 64);
    float stdv = sqrtf(vs * (1.0f/128.0f));
    float inv = 1.0f / (stdv + 1e-3f);
    bool keep = (sm != 0.0f);
    float zr[8];
#pragma unroll
    for (int w = 0; w < 8; ++w) zr[w] = keep ? (x4[u][w] - mean) * inv : 0.0f;
    float4 za = {zr[0],zr[1],zr[2],zr[3]};
    float4 zb = {zr[4],zr[5],zr[6],zr[7]};
    *(float4*)&z3g[(size_t)(i*NI + rg + 20*u)*DD + c0]     = za;
    *(float4*)&z3g[(size_t)(i*NI + rg + 20*u)*DD + c0 + 4] = zb;
  }
}

// ---------------- pair kernel: decoder both orderings + symmetric score -----
__global__ __launch_bounds__(TPB) void pair_k(
    const float* __restrict__ Qg, const float* __restrict__ Kg,
    const float* __restrict__ Vg, const float* __restrict__ e2g,
    const float* __restrict__ Whg, const float* __restrict__ Wfcg,
    const float* __restrict__ Wcsg, const float* __restrict__ Wcs2g,
    const float* __restrict__ xsg, float* __restrict__ outg)
{
  const int i = blockIdx.x, j = blockIdx.y;
  if (j < i) return;
  __shared__ __align__(16) __hip_bfloat16 slot0[NI*DD]; // x4(i,j) / phase-1 scratch
  __shared__ __align__(16) __hip_bfloat16 slot1[NI*DD]; // x4(j,i) / phase-2 scratch
  __shared__ __align__(16) float tiles[5248];
  __shared__ float red[8];
  const int t = threadIdx.x;
  const int rg = t >> 4, cg = t & 15, c0 = cg*8;
  float x4[4][8];

  attn_phase(i, j, t, Qg, Kg, Vg, e2g, Whg, Wfcg, slot0, tiles, x4);
#pragma unroll
  for (int u = 0; u < 4; ++u)
#pragma unroll
    for (int w = 0; w < 8; ++w)
      slot0[(rg + 20*u)*DD + c0 + w] = __float2bfloat16(x4[u][w]);
  __syncthreads();

  attn_phase(j, i, t, Qg, Kg, Vg, e2g, Whg, Wfcg, slot1, tiles, x4);
#pragma unroll
  for (int u = 0; u < 4; ++u)
#pragma unroll
    for (int w = 0; w < 8; ++w)
      slot1[(rg + 20*u)*DD + c0 + w] = __float2bfloat16(x4[u][w]);
  __syncthreads();

  // score: per head, G = (x4_ij @ Wcs_h) (x4_ji @ Wcs_h)^T ; sum relu(G/sqrt)
  float sc0 = 0.0f, sc1 = 0.0f;
  const float isq = 0.08838834764831845f;
  for (int h = 0; h < 2; ++h) {
    float g[4][5] = {};
    float* Wct = tiles;          // [128][16]
    float* Xi  = tiles + 2048;   // [80][20]
    float* Xj  = tiles + 3648;   // [80][20]
    for (int dc = 0; dc < 8; ++dc) {
      for (int idx = t; idx < 2048; idx += TPB) {
        int c = idx >> 4, d2 = idx & 15;
        Wct[idx] = Wcsg[(size_t)c*256 + h*128 + dc*16 + d2];
      }
      __syncthreads();
      float xiv[4] = {}, xjv[4] = {};
      for (int c = 0; c < 128; ++c) {
        float wv = Wct[c*16 + cg];
#pragma unroll
        for (int u = 0; u < 4; ++u) {
          xiv[u] = fmaf(__bfloat162float(slot0[(rg+20*u)*DD + c]), wv, xiv[u]);
          xjv[u] = fmaf(__bfloat162float(slot1[(rg+20*u)*DD + c]), wv, xjv[u]);
        }
      }
#pragma unroll
      for (int u = 0; u < 4; ++u) {
        Xi[(rg+20*u)*20 + cg] = xiv[u];
        Xj[(rg+20*u)*20 + cg] = xjv[u];
      }
      __syncthreads();
#pragma unroll
      for (int d2 = 0; d2 < 16; ++d2) {
        float xiu[4];
#pragma unroll
        for (int u = 0; u < 4; ++u) xiu[u] = Xi[(rg+20*u)*20 + d2];
#pragma unroll
        for (int v = 0; v < 5; ++v) {
          float xjvv = Xj[(cg+16*v)*20 + d2];
#pragma unroll
          for (int u = 0; u < 4; ++u) g[u][v] = fmaf(xiu[u], xjvv, g[u][v]);
        }
      }
      __syncthreads();
    }
    float loc = 0.0f;
#pragma unroll
    for (int u = 0; u < 4; ++u)
#pragma unroll
      for (int v = 0; v < 5; ++v) loc += fmaxf(g[u][v] * isq, 0.0f);
#pragma unroll
    for (int off = 1; off < 64; off <<= 1) loc += __shfl_xor(loc, off, 64);
    if ((t & 63) == 0) red[t >> 6] = loc;
    __syncthreads();
    float tot = red[0] + red[1] + red[2] + red[3] + red[4];
    if (h == 0) sc0 = tot; else sc1 = tot;
    __syncthreads();
  }
  if (t == 0) {
    float val = (sc0 * Wcs2g[0] + sc1 * Wcs2g[1]) / (xsg[i] * xsg[j]);
    outg[i*SS + j] = val;
    outg[j*SS + i] = val;
  }
}

extern "C" void kernel_launch(void* const* d_in, const int* in_sizes, int n_in,
                              void* d_out, int out_size, void* d_ws, size_t ws_size,
                              hipStream_t stream)
{
  (void)in_sizes; (void)n_in; (void)out_size; (void)ws_size;
  const float* x     = (const float*)d_in[0];
  const float* xs    = (const float*)d_in[1];
  const float* W1    = (const float*)d_in[2];
  const float* W2    = (const float*)d_in[3];
  const float* W3    = (const float*)d_in[4];
  const float* Wq_s  = (const float*)d_in[5];
  const float* Wk_s  = (const float*)d_in[6];
  const float* Wv_s  = (const float*)d_in[7];
  const float* Wh_s  = (const float*)d_in[8];
  const float* Wfc_e = (const float*)d_in[9];
  const float* Wq_c  = (const float*)d_in[10];
  const float* Wk_c  = (const float*)d_in[11];
  const float* Wv_c  = (const float*)d_in[12];
  const float* Wh_c  = (const float*)d_in[13];
  const float* Wfc_d = (const float*)d_in[14];
  const float* Wcs   = (const float*)d_in[15];
  const float* Wcs2  = (const float*)d_in[16];
  float* out = (float*)d_out;

  const int M = SS * NI; // 3840
  // Workspace layout (floats). Q/K/V reuse the h1/h2 regions (dead after MLP).
  float* h1 = (float*)d_ws;                   // M*512  [0 .. 1,966,080)
  float* h2 = h1 + (size_t)M*512;             // M*256
  float* hb = h2 + (size_t)M*256;             // M*128
  float* zb = hb + (size_t)M*128;             // M*128  (z1, later z3)
  float* e2 = zb + (size_t)M*128;             // M*128
  float* Qb = (float*)d_ws;                   // M*256 (aliases h1 lower half)
  float* Kb = Qb + (size_t)M*256;             // M*256 (aliases h1 upper half)
  float* Vb = Kb + (size_t)M*256;             // M*256 (aliases h2)
  // total footprint: M*(512+256+128+128+128) floats = ~17.7 MB

  // MLP: h = gelu(gelu(gelu(x@W1)@W2)@W3)
  hipLaunchKernelGGL((gemm_k<1>), dim3(8,60), dim3(256), 0, stream, x,  W1, h1, M, 512, 512);
  hipLaunchKernelGGL((gemm_k<1>), dim3(4,60), dim3(256), 0, stream, h1, W2, h2, M, 256, 512);
  hipLaunchKernelGGL((gemm_k<1>), dim3(2,60), dim3(256), 0, stream, h2, W3, hb, M, 128, 256);
  // z1 = item_norm(h)
  hipLaunchKernelGGL(norm_k, dim3(M), dim3(64), 0, stream, hb, zb);
  // encoder QKV (per-set)
  hipLaunchKernelGGL((gemm_k<0>), dim3(4,60), dim3(256), 0, stream, zb, Wq_s, Qb, M, 256, 128);
  hipLaunchKernelGGL((gemm_k<0>), dim3(4,60), dim3(256), 0, stream, zb, Wk_s, Kb, M, 256, 128);
  hipLaunchKernelGGL((gemm_k<0>), dim3(4,60), dim3(256), 0, stream, zb, Wv_s, Vb, M, 256, 128);
  // encoder block -> e2, z3 (z3 overwrites zb)
  hipLaunchKernelGGL(encoder_k, dim3(SS), dim3(TPB), 0, stream, Qb, Kb, Vb, hb, Wh_s, Wfc_e, e2, zb);
  // decoder QKV (per-set, from z3)
  hipLaunchKernelGGL((gemm_k<0>), dim3(4,60), dim3(256), 0, stream, zb, Wq_c, Qb, M, 256, 128);
  hipLaunchKernelGGL((gemm_k<0>), dim3(4,60), dim3(256), 0, stream, zb, Wk_c, Kb, M, 256, 128);
  hipLaunchKernelGGL((gemm_k<0>), dim3(4,60), dim3(256), 0, stream, zb, Wv_c, Vb, M, 256, 128);
  // pair decoder + symmetric score
  hipLaunchKernelGGL(pair_k, dim3(SS,SS), dim3(TPB), 0, stream,
                     Qb, Kb, Vb, e2, Wh_c, Wfc_d, Wcs, Wcs2, xs, out);
}

// Round 2
// 772.382 us; speedup vs baseline: 4.2998x; 4.2998x over previous
//
#include <hip/hip_runtime.h>
#include <hip/hip_bf16.h>

// SetMatchingModel: S=48 sets, N=80 items, D=128, H=2 heads, HS=128.
// Encoder output is pair-independent (per-set); score matrix symmetric ->
// 1176 unordered pairs. All attention/score GEMMs on MFMA bf16 16x16x32.

#define SS 48
#define NI 80
#define DD 128
#define TPB 320

typedef __attribute__((ext_vector_type(8))) short s8v;           // 8 bf16
typedef __attribute__((ext_vector_type(4))) float f4v;           // 4 f32
typedef __attribute__((ext_vector_type(4))) unsigned short u16x4;

#define MFMA(a,b,c) __builtin_amdgcn_mfma_f32_16x16x32_bf16((a),(b),(c),0,0,0)
#define SWZ(r,c) ((c) ^ (((r)&7)<<3))

__device__ __forceinline__ float gelu_f(float x){
  return 0.5f * x * (1.0f + erff(x * 0.7071067811865475f));
}
__device__ __forceinline__ unsigned short f2b(float f){
  __hip_bfloat16 b = __float2bfloat16(f);
  return reinterpret_cast<unsigned short&>(b);
}

// ---------------- generic tiled fp32 GEMM: C = act(A[M,K] @ B[K,N]) --------
template<int GELU>
__global__ __launch_bounds__(256) void gemm_k(const float* __restrict__ A,
                                              const float* __restrict__ B,
                                              float* __restrict__ C,
                                              int M, int Nn, int K)
{
  __shared__ __align__(16) float As[64*20];
  __shared__ __align__(16) float Bs[16*68];
  const int t = threadIdx.x;
  const int tx = t & 15, ty = t >> 4;
  const int bx = blockIdx.x, by = blockIdx.y;
  float acc[4][4] = {};
  for (int k0 = 0; k0 < K; k0 += 16) {
    {
      int idx = t * 4;
      int r = idx >> 4, c = idx & 15;
      *(float4*)&As[r*20 + c] =
          *(const float4*)&A[(size_t)(by*64 + r)*K + k0 + c];
      int kk = idx >> 6, col = idx & 63;
      *(float4*)&Bs[kk*68 + col] =
          *(const float4*)&B[(size_t)(k0 + kk)*Nn + bx*64 + col];
    }
    __syncthreads();
#pragma unroll
    for (int k2 = 0; k2 < 16; ++k2) {
      float ar[4], br[4];
#pragma unroll
      for (int i2 = 0; i2 < 4; ++i2) ar[i2] = As[(ty*4+i2)*20 + k2];
#pragma unroll
      for (int j2 = 0; j2 < 4; ++j2) br[j2] = Bs[k2*68 + tx*4 + j2];
#pragma unroll
      for (int i2 = 0; i2 < 4; ++i2)
#pragma unroll
        for (int j2 = 0; j2 < 4; ++j2)
          acc[i2][j2] = fmaf(ar[i2], br[j2], acc[i2][j2]);
    }
    __syncthreads();
  }
#pragma unroll
  for (int i2 = 0; i2 < 4; ++i2) {
    float4 o4;
    float* po = (float*)&o4;
#pragma unroll
    for (int j2 = 0; j2 < 4; ++j2)
      po[j2] = GELU ? gelu_f(acc[i2][j2]) : acc[i2][j2];
    *(float4*)&C[(size_t)(by*64 + ty*4 + i2)*Nn + bx*64 + tx*4] = o4;
  }
}

// ---------------- same GEMM, bf16 output (for Q/K/V) ------------------------
__global__ __launch_bounds__(256) void gemmb_k(const float* __restrict__ A,
                                               const float* __restrict__ B,
                                               unsigned short* __restrict__ C,
                                               int M, int Nn, int K)
{
  __shared__ __align__(16) float As[64*20];
  __shared__ __align__(16) float Bs[16*68];
  const int t = threadIdx.x;
  const int tx = t & 15, ty = t >> 4;
  const int bx = blockIdx.x, by = blockIdx.y;
  float acc[4][4] = {};
  for (int k0 = 0; k0 < K; k0 += 16) {
    {
      int idx = t * 4;
      int r = idx >> 4, c = idx & 15;
      *(float4*)&As[r*20 + c] =
          *(const float4*)&A[(size_t)(by*64 + r)*K + k0 + c];
      int kk = idx >> 6, col = idx & 63;
      *(float4*)&Bs[kk*68 + col] =
          *(const float4*)&B[(size_t)(k0 + kk)*Nn + bx*64 + col];
    }
    __syncthreads();
#pragma unroll
    for (int k2 = 0; k2 < 16; ++k2) {
      float ar[4], br[4];
#pragma unroll
      for (int i2 = 0; i2 < 4; ++i2) ar[i2] = As[(ty*4+i2)*20 + k2];
#pragma unroll
      for (int j2 = 0; j2 < 4; ++j2) br[j2] = Bs[k2*68 + tx*4 + j2];
#pragma unroll
      for (int i2 = 0; i2 < 4; ++i2)
#pragma unroll
        for (int j2 = 0; j2 < 4; ++j2)
          acc[i2][j2] = fmaf(ar[i2], br[j2], acc[i2][j2]);
    }
    __syncthreads();
  }
#pragma unroll
  for (int i2 = 0; i2 < 4; ++i2) {
    u16x4 o4;
#pragma unroll
    for (int j2 = 0; j2 < 4; ++j2) o4[j2] = f2b(acc[i2][j2]);
    *(u16x4*)&C[(size_t)(by*64 + ty*4 + i2)*Nn + bx*64 + tx*4] = o4;
  }
}

// ---------------- per-row item layer norm (rows of 128) ---------------------
__global__ __launch_bounds__(64) void norm_k(const float* __restrict__ in,
                                             float* __restrict__ out)
{
  const int r = blockIdx.x, t = threadIdx.x;
  float v0 = in[(size_t)r*DD + t];
  float v1 = in[(size_t)r*DD + t + 64];
  float sm = v0 + v1;
#pragma unroll
  for (int off = 1; off < 64; off <<= 1) sm += __shfl_xor(sm, off, 64);
  float mean = sm * (1.0f/128.0f);
  float d0 = v0 - mean, d1 = v1 - mean;
  float vs = d0*d0 + d1*d1;
#pragma unroll
  for (int off = 1; off < 64; off <<= 1) vs += __shfl_xor(vs, off, 64);
  float stdv = sqrtf(vs * (1.0f/128.0f));
  float inv = 1.0f / (stdv + 1e-3f);
  bool keep = (sm != 0.0f);
  out[(size_t)r*DD + t]      = keep ? d0*inv : 0.0f;
  out[(size_t)r*DD + t + 64] = keep ? d1*inv : 0.0f;
}

// ---------------- V transpose: [48*80][256] bf16 -> [48][256][96] bf16 ------
__global__ __launch_bounds__(256) void vtrans_k(const unsigned short* __restrict__ V,
                                                unsigned short* __restrict__ VT)
{
  int idx = blockIdx.x*256 + threadIdx.x;
  if (idx >= 48*256*96) return;
  int m = idx % 96; int rest = idx / 96;
  int d = rest & 255; int s = rest >> 8;
  VT[idx] = (m < NI) ? V[((size_t)(s*NI + m))*256 + d] : (unsigned short)0;
}

// ---------------- weight prep: transpose + bf16 -----------------------------
__global__ __launch_bounds__(256) void wprep_k(
    const float* __restrict__ Wh_s, const float* __restrict__ Wfc_e,
    const float* __restrict__ Wh_c, const float* __restrict__ Wfc_d,
    const float* __restrict__ Wcs,
    unsigned short* __restrict__ WhTs, unsigned short* __restrict__ WfcTe,
    unsigned short* __restrict__ WhTc, unsigned short* __restrict__ WfcTd,
    unsigned short* __restrict__ WcsT)
{
  int idx = blockIdx.x*256 + threadIdx.x;  // 131072 total
  if (idx < 32768) {            // WhTs [128][256] = Wh_s^T ([256][128])
    int c = idx >> 8, k = idx & 255;
    WhTs[idx] = f2b(Wh_s[(size_t)k*128 + c]);
  } else if (idx < 49152) {     // WfcTe [128][128]
    int i2 = idx - 32768; int c = i2 >> 7, k = i2 & 127;
    WfcTe[i2] = f2b(Wfc_e[(size_t)k*128 + c]);
  } else if (idx < 81920) {     // WhTc [128][256]
    int i2 = idx - 49152; int c = i2 >> 8, k = i2 & 255;
    WhTc[i2] = f2b(Wh_c[(size_t)k*128 + c]);
  } else if (idx < 98304) {     // WfcTd [128][128]
    int i2 = idx - 81920; int c = i2 >> 7, k = i2 & 127;
    WfcTd[i2] = f2b(Wfc_d[(size_t)k*128 + c]);
  } else if (idx < 131072) {    // WcsT [256][128] = Wcs^T ([128][256])
    int i2 = idx - 98304; int c = i2 >> 7, k = i2 & 127;
    WcsT[i2] = f2b(Wcs[(size_t)k*256 + c]);
  }
}

// ---------------- MFMA attention block for ordered (a,b) --------------------
// x4 = base[a] + MHA(Q[a],K[b],V[b]) @ Wh; z=norm(x4); x4 += gelu(z @ Wfc).
// Wave w owns rows [16w,16w+16). A-frag row ar=16w+lm; C rows r0=16w+lh*4+reg.
// All LDS traffic inside is wave-local (own 16-row stripe) -> no syncthreads.
__device__ void attn_x4(int a, int b, int w, int lm, int lh,
    const unsigned short* __restrict__ Qg, const unsigned short* __restrict__ Kg,
    const unsigned short* __restrict__ VTg, const float* __restrict__ baseg,
    const unsigned short* __restrict__ WhT, const unsigned short* __restrict__ WfcT,
    unsigned short* uP, unsigned short* uO0, unsigned short* uO1,
    f4v x4[8])
{
  const int rb = w*16, ar = rb + lm, r0 = rb + lh*4;
  const float isq = 0.08838834764831845f; // 1/sqrt(128)

#pragma unroll
  for (int h = 0; h < 2; ++h) {
    // ---- S = Q K^T ----
    const s8v* qp = (const s8v*)(Qg + ((size_t)(a*NI + ar))*256 + h*128 + lh*8);
    s8v qf0 = qp[0], qf1 = qp[4], qf2 = qp[8], qf3 = qp[12];
    f4v sA[5];
#pragma unroll
    for (int nt = 0; nt < 5; ++nt) {
      const s8v* kp = (const s8v*)(Kg + ((size_t)(b*NI + nt*16 + lm))*256 + h*128 + lh*8);
      f4v acc = {0.f,0.f,0.f,0.f};
      acc = MFMA(qf0, kp[0], acc);
      acc = MFMA(qf1, kp[4], acc);
      acc = MFMA(qf2, kp[8], acc);
      acc = MFMA(qf3, kp[12], acc);
      sA[nt] = acc;
    }
    // ---- masked softmax (mask: s != 0; max over raw row incl zeros) ----
#pragma unroll
    for (int reg = 0; reg < 4; ++reg) {
      int r = r0 + reg;
      float sv[5];
#pragma unroll
      for (int nt = 0; nt < 5; ++nt) sv[nt] = sA[nt][reg] * isq;
      float mx = sv[0];
#pragma unroll
      for (int nt = 1; nt < 5; ++nt) mx = fmaxf(mx, sv[nt]);
#pragma unroll
      for (int off = 1; off < 16; off <<= 1) mx = fmaxf(mx, __shfl_xor(mx, off, 64));
      float e[5], sum = 0.f;
#pragma unroll
      for (int nt = 0; nt < 5; ++nt) {
        e[nt] = (sv[nt] != 0.f) ? __expf(sv[nt] - mx) : 0.f;
        sum += e[nt];
      }
#pragma unroll
      for (int off = 1; off < 16; off <<= 1) sum += __shfl_xor(sum, off, 64);
      float inv = 1.f / (sum + 1e-10f);
#pragma unroll
      for (int nt = 0; nt < 5; ++nt)
        uP[r*128 + SWZ(r, nt*16 + lm)] = f2b(e[nt] * inv);
      uP[r*128 + SWZ(r, 80 + lm)] = 0;   // zero-pad m in [80,96)
    }
    // ---- O = P @ V (via VT) ----
    s8v pf0 = *(const s8v*)(uP + ar*128 + SWZ(ar, 0  + lh*8));
    s8v pf1 = *(const s8v*)(uP + ar*128 + SWZ(ar, 32 + lh*8));
    s8v pf2 = *(const s8v*)(uP + ar*128 + SWZ(ar, 64 + lh*8));
    const unsigned short* vtb = VTg + ((size_t)b*256 + h*128)*96;
    unsigned short* uo = h ? uO1 : uO0;
#pragma unroll
    for (int dt = 0; dt < 8; ++dt) {
      const s8v* vp = (const s8v*)(vtb + (dt*16 + lm)*96 + lh*8);
      f4v acc = {0.f,0.f,0.f,0.f};
      acc = MFMA(pf0, vp[0], acc);
      acc = MFMA(pf1, vp[4], acc);
      acc = MFMA(pf2, vp[8], acc);
#pragma unroll
      for (int reg = 0; reg < 4; ++reg) {
        int r = r0 + reg;
        uo[r*128 + SWZ(r, dt*16 + lm)] = f2b(acc[reg]);
      }
    }
  }

  // ---- x4 = O @ Wh + base ----
  s8v of[8];
#pragma unroll
  for (int ks = 0; ks < 4; ++ks) {
    of[ks]     = *(const s8v*)(uO0 + ar*128 + SWZ(ar, ks*32 + lh*8));
    of[ks + 4] = *(const s8v*)(uO1 + ar*128 + SWZ(ar, ks*32 + lh*8));
  }
#pragma unroll
  for (int dt = 0; dt < 8; ++dt) {
    const s8v* wp = (const s8v*)(WhT + (dt*16 + lm)*256 + lh*8);
    f4v acc = {0.f,0.f,0.f,0.f};
#pragma unroll
    for (int ks = 0; ks < 8; ++ks) acc = MFMA(of[ks], wp[ks*4], acc);
    x4[dt] = acc;
  }
#pragma unroll
  for (int reg = 0; reg < 4; ++reg) {
    int r = r0 + reg;
#pragma unroll
    for (int dt = 0; dt < 8; ++dt)
      x4[dt][reg] += baseg[((size_t)(a*NI + r))*128 + dt*16 + lm];
  }

  // ---- z = norm(x4) -> uO0 ----
#pragma unroll
  for (int reg = 0; reg < 4; ++reg) {
    int r = r0 + reg;
    float sm = 0.f;
#pragma unroll
    for (int dt = 0; dt < 8; ++dt) sm += x4[dt][reg];
#pragma unroll
    for (int off = 1; off < 16; off <<= 1) sm += __shfl_xor(sm, off, 64);
    float mean = sm * (1.0f/128.0f);
    float vs = 0.f;
#pragma unroll
    for (int dt = 0; dt < 8; ++dt) { float d = x4[dt][reg] - mean; vs = fmaf(d,d,vs); }
#pragma unroll
    for (int off = 1; off < 16; off <<= 1) vs += __shfl_xor(vs, off, 64);
    float inv = 1.f / (sqrtf(vs * (1.0f/128.0f)) + 1e-3f);
    bool keep = (sm != 0.f);
#pragma unroll
    for (int dt = 0; dt < 8; ++dt)
      uO0[r*128 + SWZ(r, dt*16 + lm)] = f2b(keep ? (x4[dt][reg]-mean)*inv : 0.f);
  }
  // ---- x4 += gelu(z @ Wfc) ----
  s8v zf[4];
#pragma unroll
  for (int ks = 0; ks < 4; ++ks)
    zf[ks] = *(const s8v*)(uO0 + ar*128 + SWZ(ar, ks*32 + lh*8));
#pragma unroll
  for (int dt = 0; dt < 8; ++dt) {
    const s8v* wp = (const s8v*)(WfcT + (dt*16 + lm)*128 + lh*8);
    f4v acc = {0.f,0.f,0.f,0.f};
#pragma unroll
    for (int ks = 0; ks < 4; ++ks) acc = MFMA(zf[ks], wp[ks*4], acc);
#pragma unroll
    for (int reg = 0; reg < 4; ++reg) x4[dt][reg] += gelu_f(acc[reg]);
  }
}

// ---------------- encoder: per-set block, writes e2 (f32) + z3 (f32) --------
__global__ __launch_bounds__(TPB) void enc2_k(
    const unsigned short* __restrict__ Qg, const unsigned short* __restrict__ Kg,
    const unsigned short* __restrict__ VTg, const float* __restrict__ hb,
    const unsigned short* __restrict__ WhT, const unsigned short* __restrict__ WfcT,
    float* __restrict__ e2, float* __restrict__ z3)
{
  __shared__ __align__(16) unsigned short lds[30720];
  unsigned short* uP  = lds;
  unsigned short* uO0 = lds + 10240;
  unsigned short* uO1 = lds + 20480;
  const int t = threadIdx.x;
  const int w = t >> 6, lm = t & 15, lh = (t >> 4) & 3;
  const int r0 = w*16 + lh*4;
  const int i = blockIdx.x;
  f4v x4[8];
  attn_x4(i, i, w, lm, lh, Qg, Kg, VTg, hb, WhT, WfcT, uP, uO0, uO1, x4);
#pragma unroll
  for (int reg = 0; reg < 4; ++reg) {
    int r = r0 + reg;
    size_t grow = (size_t)(i*NI + r)*128;
    float sm = 0.f;
#pragma unroll
    for (int dt = 0; dt < 8; ++dt) { e2[grow + dt*16 + lm] = x4[dt][reg]; sm += x4[dt][reg]; }
#pragma unroll
    for (int off = 1; off < 16; off <<= 1) sm += __shfl_xor(sm, off, 64);
    float mean = sm * (1.0f/128.0f);
    float vs = 0.f;
#pragma unroll
    for (int dt = 0; dt < 8; ++dt) { float d = x4[dt][reg] - mean; vs = fmaf(d,d,vs); }
#pragma unroll
    for (int off = 1; off < 16; off <<= 1) vs += __shfl_xor(vs, off, 64);
    float inv = 1.f / (sqrtf(vs * (1.0f/128.0f)) + 1e-3f);
    bool keep = (sm != 0.f);
#pragma unroll
    for (int dt = 0; dt < 8; ++dt)
      z3[grow + dt*16 + lm] = keep ? (x4[dt][reg]-mean)*inv : 0.f;
  }
}

// ---------------- pair kernel: both orderings + symmetric score -------------
__global__ __launch_bounds__(TPB, 3) void pair2_k(
    const unsigned short* __restrict__ Qg, const unsigned short* __restrict__ Kg,
    const unsigned short* __restrict__ VTg, const float* __restrict__ e2,
    const unsigned short* __restrict__ WhT, const unsigned short* __restrict__ WfcT,
    const unsigned short* __restrict__ WcsT, const float* __restrict__ Wcs2,
    const float* __restrict__ xsg, float* __restrict__ outg)
{
  __shared__ __align__(16) unsigned short lds[40960];  // 80 KiB exactly
  unsigned short* buf0 = lds;            // P(i,j) then x4(i,j)
  unsigned short* buf1 = lds + 10240;    // P(j,i) then x4(j,i)
  unsigned short* buf2 = lds + 20480;    // O0 / z / xh_i
  unsigned short* buf3 = lds + 30720;    // O1 / xh_j

  const int t = threadIdx.x;
  const int w = t >> 6, lm = t & 15, lh = (t >> 4) & 3;
  const int ar = w*16 + lm, r0 = w*16 + lh*4;
  const float isq = 0.08838834764831845f;

  // triangular decode: bid -> (i,j), i<=j
  int bid = blockIdx.x;
  int i = (int)(0.5f*(97.0f - sqrtf(9409.0f - 8.0f*(float)bid)));
  if (i > 47) i = 47; if (i < 0) i = 0;
  while (i*SS - i*(i-1)/2 > bid) --i;
  while ((i+1)*SS - (i+1)*i/2 <= bid) ++i;
  int j = i + (bid - (i*SS - i*(i-1)/2));

  f4v x4[8];
  attn_x4(i, j, w, lm, lh, Qg, Kg, VTg, e2, WhT, WfcT, buf0, buf2, buf3, x4);
#pragma unroll
  for (int reg = 0; reg < 4; ++reg) {
    int r = r0 + reg;
#pragma unroll
    for (int dt = 0; dt < 8; ++dt)
      buf0[r*128 + SWZ(r, dt*16 + lm)] = f2b(x4[dt][reg]);
  }
  attn_x4(j, i, w, lm, lh, Qg, Kg, VTg, e2, WhT, WfcT, buf1, buf2, buf3, x4);
#pragma unroll
  for (int reg = 0; reg < 4; ++reg) {
    int r = r0 + reg;
#pragma unroll
    for (int dt = 0; dt < 8; ++dt)
      buf1[r*128 + SWZ(r, dt*16 + lm)] = f2b(x4[dt][reg]);
  }

  // ---- score: per head, G = xh_i @ xh_j^T; sum relu(G/sqrt(HS)) ----
  float sc0 = 0.f, sc1 = 0.f;
  for (int h = 0; h < 2; ++h) {
    s8v xf[4];
#pragma unroll
    for (int ks = 0; ks < 4; ++ks)
      xf[ks] = *(const s8v*)(buf0 + ar*128 + SWZ(ar, ks*32 + lh*8));
#pragma unroll
    for (int dt = 0; dt < 8; ++dt) {
      const s8v* wp = (const s8v*)(WcsT + (size_t)(h*128 + dt*16 + lm)*128 + lh*8);
      f4v acc = {0.f,0.f,0.f,0.f};
#pragma unroll
      for (int ks = 0; ks < 4; ++ks) acc = MFMA(xf[ks], wp[ks*4], acc);
#pragma unroll
      for (int reg = 0; reg < 4; ++reg) {
        int r = r0 + reg;
        buf2[r*128 + SWZ(r, dt*16 + lm)] = f2b(acc[reg]);
      }
    }
#pragma unroll
    for (int ks = 0; ks < 4; ++ks)
      xf[ks] = *(const s8v*)(buf1 + ar*128 + SWZ(ar, ks*32 + lh*8));
#pragma unroll
    for (int dt = 0; dt < 8; ++dt) {
      const s8v* wp = (const s8v*)(WcsT + (size_t)(h*128 + dt*16 + lm)*128 + lh*8);
      f4v acc = {0.f,0.f,0.f,0.f};
#pragma unroll
      for (int ks = 0; ks < 4; ++ks) acc = MFMA(xf[ks], wp[ks*4], acc);
#pragma unroll
      for (int reg = 0; reg < 4; ++reg) {
        int r = r0 + reg;
        buf3[r*128 + SWZ(r, dt*16 + lm)] = f2b(acc[reg]);
      }
    }
    __syncthreads();
    // G rows stripe x 5 col-tiles
    s8v gf[4];
#pragma unroll
    for (int ks = 0; ks < 4; ++ks)
      gf[ks] = *(const s8v*)(buf2 + ar*128 + SWZ(ar, ks*32 + lh*8));
    float loc = 0.f;
#pragma unroll
    for (int nt = 0; nt < 5; ++nt) {
      f4v acc = {0.f,0.f,0.f,0.f};
#pragma unroll
      for (int ks = 0; ks < 4; ++ks) {
        int br = nt*16 + lm;
        s8v bf = *(const s8v*)(buf3 + br*128 + SWZ(br, ks*32 + lh*8));
        acc = MFMA(gf[ks], bf, acc);
      }
#pragma unroll
      for (int reg = 0; reg < 4; ++reg) loc += fmaxf(acc[reg]*isq, 0.f);
    }
    if (h == 0) sc0 = loc; else sc1 = loc;
    __syncthreads();
  }
#pragma unroll
  for (int off = 1; off < 64; off <<= 1) {
    sc0 += __shfl_xor(sc0, off, 64);
    sc1 += __shfl_xor(sc1, off, 64);
  }
  float* red = (float*)(lds + 20480);   // buf2 region (dead now)
  if ((t & 63) == 0) { red[w] = sc0; red[w + 8] = sc1; }
  __syncthreads();
  if (t == 0) {
    float a0 = 0.f, a1 = 0.f;
#pragma unroll
    for (int q = 0; q < 5; ++q) { a0 += red[q]; a1 += red[q + 8]; }
    float val = (a0 * Wcs2[0] + a1 * Wcs2[1]) / (xsg[i] * xsg[j]);
    outg[i*SS + j] = val;
    outg[j*SS + i] = val;
  }
}

extern "C" void kernel_launch(void* const* d_in, const int* in_sizes, int n_in,
                              void* d_out, int out_size, void* d_ws, size_t ws_size,
                              hipStream_t stream)
{
  (void)in_sizes; (void)n_in; (void)out_size; (void)ws_size;
  const float* x     = (const float*)d_in[0];
  const float* xs    = (const float*)d_in[1];
  const float* W1    = (const float*)d_in[2];
  const float* W2    = (const float*)d_in[3];
  const float* W3    = (const float*)d_in[4];
  const float* Wq_s  = (const float*)d_in[5];
  const float* Wk_s  = (const float*)d_in[6];
  const float* Wv_s  = (const float*)d_in[7];
  const float* Wh_s  = (const float*)d_in[8];
  const float* Wfc_e = (const float*)d_in[9];
  const float* Wq_c  = (const float*)d_in[10];
  const float* Wk_c  = (const float*)d_in[11];
  const float* Wv_c  = (const float*)d_in[12];
  const float* Wh_c  = (const float*)d_in[13];
  const float* Wfc_d = (const float*)d_in[14];
  const float* Wcs   = (const float*)d_in[15];
  const float* Wcs2  = (const float*)d_in[16];
  float* out = (float*)d_out;

  const int M = SS * NI; // 3840
  // fp32 regions
  float* h1 = (float*)d_ws;            // M*512
  float* h2 = h1 + (size_t)M*512;      // M*256
  float* hb = h2 + (size_t)M*256;      // M*128
  float* zb = hb + (size_t)M*128;      // M*128 (z1, later z3)
  float* e2 = zb + (size_t)M*128;      // M*128
  // bf16 regions (alias dead fp32 space)
  unsigned short* Qb = (unsigned short*)h1;       // M*256 (h1 dead after MLP2)
  unsigned short* Kb = Qb + (size_t)M*256;
  unsigned short* Vb = Kb + (size_t)M*256;        // 5.9MB <= h1's 7.86MB
  unsigned short* VT = (unsigned short*)h2;       // 48*256*96 (h2 dead after MLP3)
  unsigned short* WhTs  = VT + 48*256*96;
  unsigned short* WfcTe = WhTs + 128*256;
  unsigned short* WhTc  = WfcTe + 128*128;
  unsigned short* WfcTd = WhTc + 128*256;
  unsigned short* WcsT  = WfcTd + 128*128;        // total 2.62MB <= h2's 3.93MB

  // MLP
  hipLaunchKernelGGL((gemm_k<1>), dim3(8,60), dim3(256), 0, stream, x,  W1, h1, M, 512, 512);
  hipLaunchKernelGGL((gemm_k<1>), dim3(4,60), dim3(256), 0, stream, h1, W2, h2, M, 256, 512);
  hipLaunchKernelGGL((gemm_k<1>), dim3(2,60), dim3(256), 0, stream, h2, W3, hb, M, 128, 256);
  hipLaunchKernelGGL(norm_k, dim3(M), dim3(64), 0, stream, hb, zb);
  hipLaunchKernelGGL(wprep_k, dim3(512), dim3(256), 0, stream,
                     Wh_s, Wfc_e, Wh_c, Wfc_d, Wcs, WhTs, WfcTe, WhTc, WfcTd, WcsT);
  // encoder QKV (bf16)
  hipLaunchKernelGGL(gemmb_k, dim3(4,60), dim3(256), 0, stream, zb, Wq_s, Qb, M, 256, 128);
  hipLaunchKernelGGL(gemmb_k, dim3(4,60), dim3(256), 0, stream, zb, Wk_s, Kb, M, 256, 128);
  hipLaunchKernelGGL(gemmb_k, dim3(4,60), dim3(256), 0, stream, zb, Wv_s, Vb, M, 256, 128);
  hipLaunchKernelGGL(vtrans_k, dim3(4608), dim3(256), 0, stream, Vb, VT);
  hipLaunchKernelGGL(enc2_k, dim3(SS), dim3(TPB), 0, stream, Qb, Kb, VT, hb, WhTs, WfcTe, e2, zb);
  // decoder QKV (bf16)
  hipLaunchKernelGGL(gemmb_k, dim3(4,60), dim3(256), 0, stream, zb, Wq_c, Qb, M, 256, 128);
  hipLaunchKernelGGL(gemmb_k, dim3(4,60), dim3(256), 0, stream, zb, Wk_c, Kb, M, 256, 128);
  hipLaunchKernelGGL(gemmb_k, dim3(4,60), dim3(256), 0, stream, zb, Wv_c, Vb, M, 256, 128);
  hipLaunchKernelGGL(vtrans_k, dim3(4608), dim3(256), 0, stream, Vb, VT);
  // pair decoder + symmetric score
  hipLaunchKernelGGL(pair2_k, dim3(1176), dim3(TPB), 0, stream,
                     Qb, Kb, VT, e2, WhTc, WfcTd, WcsT, Wcs2, xs, out);
}

// Round 3
// 564.138 us; speedup vs baseline: 5.8870x; 1.3691x over previous
//
#include <hip/hip_runtime.h>
#include <hip/hip_bf16.h>

// SetMatchingModel S=48,N=80,D=128,H=2,HS=128.
// Encoder is pair-independent (per-set); score symmetric -> 1176 pairs.
// v3: 640-thr pair blocks (both orderings concurrent), LDS-staged K/VT/weights
// shared by all 10 waves, 80KiB LDS = 2 blocks/CU, bf16 MFMA everywhere.

#define SS 48
#define NI 80

typedef unsigned short us;
typedef __attribute__((ext_vector_type(8))) short s8v;   // 8 bf16
typedef __attribute__((ext_vector_type(4))) float f4v;   // 4 f32

#define MFMA(a,b,c) __builtin_amdgcn_mfma_f32_16x16x32_bf16((a),(b),(c),0,0,0)

__device__ __forceinline__ float gelu_f(float x){
  return 0.5f * x * (1.0f + erff(x * 0.7071067811865475f));
}
__device__ __forceinline__ us f2b(float f){
  __hip_bfloat16 b = __float2bfloat16(f);
  return reinterpret_cast<us&>(b);
}
__device__ __forceinline__ s8v zero8(){ s8v v = {0,0,0,0,0,0,0,0}; return v; }

// ---------------- bf16 MFMA GEMM: C = gelu(A[M,K] @ B[K,N]) -----------------
// A: f32 or bf16 (converted in staging); B: f32 [K][N] (transposed in staging).
template<int ABF16, int OUTF32>
__global__ __launch_bounds__(256) void mgemm_k(const void* __restrict__ Ap,
    const float* __restrict__ B, void* __restrict__ Cp, int N, int K)
{
  __shared__ __align__(16) char lds[10240]; // As[64][80B] + Bs[64][80B]
  char* As = lds; char* Bs = lds + 5120;
  const int t = threadIdx.x;
  const int wv = t >> 6, lm = t & 15, lh = (t >> 4) & 3;
  const int bx = blockIdx.x, by = blockIdx.y;
  const int ar = wv*16 + lm, r0 = wv*16 + lh*4;
  f4v acc[4];
#pragma unroll
  for (int ct = 0; ct < 4; ++ct) acc[ct] = {0.f,0.f,0.f,0.f};
  const int rA = t >> 2, kcA = (t & 3) << 3;
  const int kkB = t >> 3, nnB = (t & 7) << 3;
  for (int k0 = 0; k0 < K; k0 += 32) {
    __syncthreads();
    if (ABF16) {
      s8v v = *(const s8v*)((const us*)Ap + (size_t)(by*64 + rA)*K + k0 + kcA);
      *(s8v*)(As + rA*80 + kcA*2) = v;
    } else {
      const float* ap = (const float*)Ap + (size_t)(by*64 + rA)*K + k0 + kcA;
      float4 v0 = *(const float4*)ap, v1 = *(const float4*)(ap + 4);
      us tmp[8] = {f2b(v0.x),f2b(v0.y),f2b(v0.z),f2b(v0.w),
                   f2b(v1.x),f2b(v1.y),f2b(v1.z),f2b(v1.w)};
      *(s8v*)(As + rA*80 + kcA*2) = *(const s8v*)tmp;
    }
    {
      const float* bp = B + (size_t)(k0 + kkB)*N + bx*64 + nnB;
      float4 w0 = *(const float4*)bp, w1 = *(const float4*)(bp + 4);
      float w8[8] = {w0.x,w0.y,w0.z,w0.w,w1.x,w1.y,w1.z,w1.w};
#pragma unroll
      for (int q = 0; q < 8; ++q)
        *(us*)(Bs + (nnB + q)*80 + kkB*2) = f2b(w8[q]);
    }
    __syncthreads();
    s8v af = *(const s8v*)(As + ar*80 + lh*16);
#pragma unroll
    for (int ct = 0; ct < 4; ++ct) {
      s8v bf = *(const s8v*)(Bs + (ct*16 + lm)*80 + lh*16);
      acc[ct] = MFMA(af, bf, acc[ct]);
    }
  }
#pragma unroll
  for (int ct = 0; ct < 4; ++ct)
#pragma unroll
    for (int reg = 0; reg < 4; ++reg) {
      size_t r = by*64 + r0 + reg;
      int c = bx*64 + ct*16 + lm;
      float v = gelu_f(acc[ct][reg]);
      if (OUTF32) ((float*)Cp)[r*N + c] = v;
      else ((us*)Cp)[r*N + c] = f2b(v);
    }
}

// ---------------- fused QKV GEMM (K=128, N=256 each), V -> VT scatter -------
__global__ __launch_bounds__(256) void qkv_k(const us* __restrict__ A,
    const float* __restrict__ Wq, const float* __restrict__ Wk,
    const float* __restrict__ Wv, us* __restrict__ Qb, us* __restrict__ Kb,
    us* __restrict__ VT)
{
  __shared__ __align__(16) char lds[10240];
  char* As = lds; char* Bs = lds + 5120;
  const int t = threadIdx.x;
  const int wv = t >> 6, lm = t & 15, lh = (t >> 4) & 3;
  const int bx = blockIdx.x, by = blockIdx.y;
  const int sel = bx >> 2, bxx = bx & 3;
  const float* B = sel == 0 ? Wq : (sel == 1 ? Wk : Wv);
  const int ar = wv*16 + lm, r0 = wv*16 + lh*4;
  f4v acc[4];
#pragma unroll
  for (int ct = 0; ct < 4; ++ct) acc[ct] = {0.f,0.f,0.f,0.f};
  const int rA = t >> 2, kcA = (t & 3) << 3;
  const int kkB = t >> 3, nnB = (t & 7) << 3;
#pragma unroll
  for (int k0 = 0; k0 < 128; k0 += 32) {
    __syncthreads();
    {
      s8v v = *(const s8v*)(A + (size_t)(by*64 + rA)*128 + k0 + kcA);
      *(s8v*)(As + rA*80 + kcA*2) = v;
      const float* bp = B + (size_t)(k0 + kkB)*256 + bxx*64 + nnB;
      float4 w0 = *(const float4*)bp, w1 = *(const float4*)(bp + 4);
      float w8[8] = {w0.x,w0.y,w0.z,w0.w,w1.x,w1.y,w1.z,w1.w};
#pragma unroll
      for (int q = 0; q < 8; ++q)
        *(us*)(Bs + (nnB + q)*80 + kkB*2) = f2b(w8[q]);
    }
    __syncthreads();
    s8v af = *(const s8v*)(As + ar*80 + lh*16);
#pragma unroll
    for (int ct = 0; ct < 4; ++ct) {
      s8v bf = *(const s8v*)(Bs + (ct*16 + lm)*80 + lh*16);
      acc[ct] = MFMA(af, bf, acc[ct]);
    }
  }
  if (sel < 2) {
    us* O = sel ? Kb : Qb;
#pragma unroll
    for (int ct = 0; ct < 4; ++ct)
#pragma unroll
      for (int reg = 0; reg < 4; ++reg)
        O[(size_t)(by*64 + r0 + reg)*256 + bxx*64 + ct*16 + lm] = f2b(acc[ct][reg]);
  } else {
#pragma unroll
    for (int ct = 0; ct < 4; ++ct)
#pragma unroll
      for (int reg = 0; reg < 4; ++reg) {
        int r = by*64 + r0 + reg;
        int s = r / 80, m = r % 80;
        int d = bxx*64 + ct*16 + lm;
        VT[((size_t)s*256 + d)*80 + m] = f2b(acc[ct][reg]);
      }
  }
}

// ---------------- per-row item layer norm, bf16 out -------------------------
__global__ __launch_bounds__(64) void norm_k(const float* __restrict__ in,
                                             us* __restrict__ out)
{
  const int r = blockIdx.x, t = threadIdx.x;
  float v0 = in[(size_t)r*128 + t];
  float v1 = in[(size_t)r*128 + t + 64];
  float sm = v0 + v1;
#pragma unroll
  for (int off = 1; off < 64; off <<= 1) sm += __shfl_xor(sm, off, 64);
  float mean = sm * (1.0f/128.0f);
  float d0 = v0 - mean, d1 = v1 - mean;
  float vs = d0*d0 + d1*d1;
#pragma unroll
  for (int off = 1; off < 64; off <<= 1) vs += __shfl_xor(vs, off, 64);
  float inv = 1.0f / (sqrtf(vs * (1.0f/128.0f)) + 1e-3f);
  bool keep = (sm != 0.0f);
  out[(size_t)r*128 + t]      = f2b(keep ? d0*inv : 0.0f);
  out[(size_t)r*128 + t + 64] = f2b(keep ? d1*inv : 0.0f);
}

// ---------------- weight prep: transpose + bf16 -----------------------------
__global__ __launch_bounds__(256) void wprep_k(
    const float* __restrict__ Wh_s, const float* __restrict__ Wfc_e,
    const float* __restrict__ Wh_c, const float* __restrict__ Wfc_d,
    const float* __restrict__ Wcs,
    us* __restrict__ WhTs, us* __restrict__ WfcTe,
    us* __restrict__ WhTc, us* __restrict__ WfcTd, us* __restrict__ WcsT)
{
  int idx = blockIdx.x*256 + threadIdx.x;  // 131072 total
  if (idx < 32768) {            // WhTs [128][256] = Wh_s^T
    int c = idx >> 8, k = idx & 255;
    WhTs[idx] = f2b(Wh_s[(size_t)k*128 + c]);
  } else if (idx < 49152) {     // WfcTe [128][128]
    int i2 = idx - 32768; int c = i2 >> 7, k = i2 & 127;
    WfcTe[i2] = f2b(Wfc_e[(size_t)k*128 + c]);
  } else if (idx < 81920) {     // WhTc [128][256]
    int i2 = idx - 49152; int c = i2 >> 8, k = i2 & 255;
    WhTc[i2] = f2b(Wh_c[(size_t)k*128 + c]);
  } else if (idx < 98304) {     // WfcTd [128][128]
    int i2 = idx - 81920; int c = i2 >> 7, k = i2 & 127;
    WfcTd[i2] = f2b(Wfc_d[(size_t)k*128 + c]);
  } else if (idx < 131072) {    // WcsT [256][128] = Wcs^T
    int i2 = idx - 98304; int c = i2 >> 7, k = i2 & 127;
    WcsT[i2] = f2b(Wcs[(size_t)k*256 + c]);
  }
}

// ---------------- fused encoder/pair kernel ---------------------------------
// 640 threads = 2 wave-groups of 5 waves. Group g computes ordering
// (a,b) = g ? (j,i) : (i,j). LDS per group: X (20KB: K / VT / weight-half /
// xh1), Y (20KB: P / O / z / x4 / xh0). Weight slices staged once into
// X0+X1, shared by both groups (lockstep barriers).
template<int PAIR>
__global__ __launch_bounds__(640, 5) void encdec_k(
    const us* __restrict__ Qg, const us* __restrict__ Kg,
    const us* __restrict__ VTg, const float* __restrict__ baseg,
    const us* __restrict__ WhT, const us* __restrict__ WfcT,
    const us* __restrict__ WcsT, const float* __restrict__ Wcs2,
    const float* __restrict__ xsg,
    float* __restrict__ e2p, us* __restrict__ z3b, float* __restrict__ outg)
{
  __shared__ __align__(16) char lds[81920];
  const int t = threadIdx.x;
  const int g = (t >= 320) ? 1 : 0;
  const int tg = t - g*320;
  const int lm = t & 15, lh = (t >> 4) & 3;
  const int wv = tg >> 6;
  const int ar = wv*16 + lm, r0 = wv*16 + lh*4;
  char* X = lds + g*40960;
  char* Y = X + 20480;
  char* W0 = lds;
  char* W1 = lds + 40960;
  const float isq = 0.08838834764831845f;

  int i, j;
  if (PAIR) {
    int bid0 = blockIdx.x;
    int bid = (bid0 & 7) * 147 + (bid0 >> 3);     // XCD-chunk swizzle (1176=8*147)
    int ii = (int)(0.5f*(97.0f - sqrtf(9409.0f - 8.0f*(float)bid)));
    if (ii > 47) ii = 47; if (ii < 0) ii = 0;
    while (ii*SS - ii*(ii-1)/2 > bid) --ii;
    while ((ii+1)*SS - (ii+1)*ii/2 <= bid) ++ii;
    i = ii; j = ii + (bid - (ii*SS - ii*(ii-1)/2));
  } else { i = blockIdx.x; j = i; }
  const int a = g ? j : i, b = g ? i : j;

  f4v x4[8];
#pragma unroll
  for (int dt = 0; dt < 8; ++dt) x4[dt] = {0.f,0.f,0.f,0.f};

#pragma unroll
  for (int h = 0; h < 2; ++h) {
    // ---- stage K_h[b] -> X ([80][128] bf16, xor-swizzled) ----
    __syncthreads();
#pragma unroll
    for (int q = 0; q < 4; ++q) {
      int qq = tg + q*320;
      int row = qq >> 4, colb = (qq & 15) << 4;
      s8v v = *(const s8v*)(Kg + (((size_t)(b*NI + row)) << 8) + h*128 + (colb >> 1));
      *(s8v*)(X + row*256 + (colb ^ ((row & 7) << 4))) = v;
    }
    // Q frags (global, own rows)
    const us* qrow = Qg + (((size_t)(a*NI + ar)) << 8) + h*128 + lh*8;
    s8v qf[4];
#pragma unroll
    for (int ks = 0; ks < 4; ++ks) qf[ks] = *(const s8v*)(qrow + ks*32);
    __syncthreads();
    // ---- S = Q K^T ----
    f4v sA[5];
#pragma unroll
    for (int nt = 0; nt < 5; ++nt) {
      int row = nt*16 + lm;
      f4v acc = {0.f,0.f,0.f,0.f};
#pragma unroll
      for (int ks = 0; ks < 4; ++ks) {
        s8v kf = *(const s8v*)(X + row*256 + ((ks*64 + lh*16) ^ ((row & 7) << 4)));
        acc = MFMA(qf[ks], kf, acc);
      }
      sA[nt] = acc;
    }
    // ---- masked softmax (mask: s!=0; max over raw row) -> P (Y) ----
#pragma unroll
    for (int reg = 0; reg < 4; ++reg) {
      int r = r0 + reg;
      float sv[5];
#pragma unroll
      for (int nt = 0; nt < 5; ++nt) sv[nt] = sA[nt][reg] * isq;
      float mx = sv[0];
#pragma unroll
      for (int nt = 1; nt < 5; ++nt) mx = fmaxf(mx, sv[nt]);
#pragma unroll
      for (int off = 1; off < 16; off <<= 1) mx = fmaxf(mx, __shfl_xor(mx, off, 64));
      float e[5], sum = 0.f;
#pragma unroll
      for (int nt = 0; nt < 5; ++nt) {
        e[nt] = (sv[nt] != 0.f) ? __expf(sv[nt] - mx) : 0.f;
        sum += e[nt];
      }
#pragma unroll
      for (int off = 1; off < 16; off <<= 1) sum += __shfl_xor(sum, off, 64);
      float inv = 1.f / (sum + 1e-10f);
#pragma unroll
      for (int nt = 0; nt < 5; ++nt)
        *(us*)(Y + r*256 + ((2*(nt*16 + lm)) ^ ((r & 7) << 4))) = f2b(e[nt] * inv);
    }
    // P frags (own row; m 80..95 handled by zero frags, no pad stored)
    s8v pf0 = *(const s8v*)(Y + ar*256 + ((lh*16) ^ ((ar & 7) << 4)));
    s8v pf1 = *(const s8v*)(Y + ar*256 + ((64 + lh*16) ^ ((ar & 7) << 4)));
    s8v pf2 = zero8();
    if (lh < 2) pf2 = *(const s8v*)(Y + ar*256 + ((128 + lh*16) ^ ((ar & 7) << 4)));
    // ---- stage VT_h[b] -> X ([128][80] bf16, 16B-rotated rows) ----
    __syncthreads();
#pragma unroll
    for (int q = 0; q < 4; ++q) {
      int qq = tg + q*320;
      int row = qq / 10, cb = (qq % 10) << 4;
      int off = cb + ((row % 10) << 4); if (off >= 160) off -= 160;
      s8v v = *(const s8v*)(VTg + ((size_t)(b*256 + h*128 + row))*80 + (cb >> 1));
      *(s8v*)(X + row*160 + off) = v;
    }
    __syncthreads();
    // ---- O = P @ V -> Y (overwrites P; pf already in regs) ----
#pragma unroll
    for (int dt = 0; dt < 8; ++dt) {
      int row = dt*16 + lm;
      int rm = (row % 10) << 4;
      f4v acc = {0.f,0.f,0.f,0.f};
      {
        int off = lh*16 + rm; if (off >= 160) off -= 160;
        s8v vp = *(const s8v*)(X + row*160 + off);
        acc = MFMA(pf0, vp, acc);
      }
      {
        int off = 64 + lh*16 + rm; if (off >= 160) off -= 160;
        s8v vp = *(const s8v*)(X + row*160 + off);
        acc = MFMA(pf1, vp, acc);
      }
      {
        s8v vp = zero8();
        if (lh < 2) {
          int off = 128 + lh*16 + rm; if (off >= 160) off -= 160;
          vp = *(const s8v*)(X + row*160 + off);
        }
        acc = MFMA(pf2, vp, acc);
      }
#pragma unroll
      for (int reg = 0; reg < 4; ++reg) {
        int r = r0 + reg;
        *(us*)(Y + r*256 + ((2*(dt*16 + lm)) ^ ((r & 7) << 4))) = f2b(acc[reg]);
      }
    }
    // of frags (own row)
    s8v of[4];
#pragma unroll
    for (int ks = 0; ks < 4; ++ks)
      of[ks] = *(const s8v*)(Y + ar*256 + ((ks*64 + lh*16) ^ ((ar & 7) << 4)));
    // ---- stage WhT head slice (32KB) -> W0+W1 (block-shared) ----
    __syncthreads();
    for (int qq = t; qq < 2048; qq += 640) {
      int row = qq >> 4, colb = (qq & 15) << 4;
      s8v v = *(const s8v*)(WhT + (size_t)row*256 + h*128 + (colb >> 1));
      char* dst = row < 80 ? W0 : W1;
      int r2 = row < 80 ? row : row - 80;
      *(s8v*)(dst + r2*256 + (colb ^ ((row & 7) << 4))) = v;
    }
    __syncthreads();
    // ---- x4 += O_h @ Wh_h ----
#pragma unroll
    for (int dt = 0; dt < 8; ++dt) {
      int row = dt*16 + lm;
      const char* base = dt < 5 ? W0 : W1;
      int r2 = dt < 5 ? row : row - 80;
#pragma unroll
      for (int ks = 0; ks < 4; ++ks) {
        s8v wf = *(const s8v*)(base + r2*256 + ((ks*64 + lh*16) ^ ((row & 7) << 4)));
        x4[dt] = MFMA(of[ks], wf, x4[dt]);
      }
    }
  } // heads

  // ---- residual ----
  if (PAIR) {
#pragma unroll
    for (int reg = 0; reg < 4; ++reg) {
      int r = r0 + reg;
      const f4v* bp = (const f4v*)(baseg + (((size_t)(a*NI + r)) << 7) + lm*8);
      f4v b0 = bp[0], b1 = bp[1];
#pragma unroll
      for (int dt = 0; dt < 4; ++dt) { x4[dt][reg] += b0[dt]; x4[dt+4][reg] += b1[dt]; }
    }
  } else {
#pragma unroll
    for (int reg = 0; reg < 4; ++reg) {
      int r = r0 + reg;
#pragma unroll
      for (int dt = 0; dt < 8; ++dt)
        x4[dt][reg] += baseg[(((size_t)(a*NI + r)) << 7) + dt*16 + lm];
    }
  }
  // ---- z = item_norm(x4) -> Y ----
#pragma unroll
  for (int reg = 0; reg < 4; ++reg) {
    int r = r0 + reg;
    float sm = 0.f;
#pragma unroll
    for (int dt = 0; dt < 8; ++dt) sm += x4[dt][reg];
#pragma unroll
    for (int off = 1; off < 16; off <<= 1) sm += __shfl_xor(sm, off, 64);
    float mean = sm * (1.0f/128.0f);
    float vs = 0.f;
#pragma unroll
    for (int dt = 0; dt < 8; ++dt) { float d = x4[dt][reg] - mean; vs = fmaf(d, d, vs); }
#pragma unroll
    for (int off = 1; off < 16; off <<= 1) vs += __shfl_xor(vs, off, 64);
    float inv = 1.f / (sqrtf(vs * (1.0f/128.0f)) + 1e-3f);
    bool keep = (sm != 0.f);
#pragma unroll
    for (int dt = 0; dt < 8; ++dt)
      *(us*)(Y + r*256 + ((2*(dt*16 + lm)) ^ ((r & 7) << 4))) = f2b(keep ? (x4[dt][reg]-mean)*inv : 0.f);
  }
  s8v zf[4];
#pragma unroll
  for (int ks = 0; ks < 4; ++ks)
    zf[ks] = *(const s8v*)(Y + ar*256 + ((ks*64 + lh*16) ^ ((ar & 7) << 4)));
  // ---- stage WfcT (32KB) -> W0+W1; x4 += gelu(z @ Wfc) ----
  __syncthreads();
  for (int qq = t; qq < 2048; qq += 640) {
    int row = qq >> 4, colb = (qq & 15) << 4;
    s8v v = *(const s8v*)(WfcT + (size_t)row*128 + (colb >> 1));
    char* dst = row < 80 ? W0 : W1;
    int r2 = row < 80 ? row : row - 80;
    *(s8v*)(dst + r2*256 + (colb ^ ((row & 7) << 4))) = v;
  }
  __syncthreads();
#pragma unroll
  for (int dt = 0; dt < 8; ++dt) {
    int row = dt*16 + lm;
    const char* base = dt < 5 ? W0 : W1;
    int r2 = dt < 5 ? row : row - 80;
    f4v acc = {0.f,0.f,0.f,0.f};
#pragma unroll
    for (int ks = 0; ks < 4; ++ks) {
      s8v wf = *(const s8v*)(base + r2*256 + ((ks*64 + lh*16) ^ ((row & 7) << 4)));
      acc = MFMA(zf[ks], wf, acc);
    }
#pragma unroll
    for (int reg = 0; reg < 4; ++reg) x4[dt][reg] += gelu_f(acc[reg]);
  }

  if (!PAIR) {
    // encoder epilogue: e2 (permuted f32) + z3 (bf16 std). group0 only.
    if (g == 0) {
#pragma unroll
      for (int reg = 0; reg < 4; ++reg) {
        int r = r0 + reg;
        size_t gb = ((size_t)(i*NI + r)) << 7;
        float tmp[8]; float sm = 0.f;
#pragma unroll
        for (int dt = 0; dt < 8; ++dt) { tmp[dt] = x4[dt][reg]; sm += tmp[dt]; }
        *(float4*)(e2p + gb + lm*8)     = make_float4(tmp[0],tmp[1],tmp[2],tmp[3]);
        *(float4*)(e2p + gb + lm*8 + 4) = make_float4(tmp[4],tmp[5],tmp[6],tmp[7]);
#pragma unroll
        for (int off = 1; off < 16; off <<= 1) sm += __shfl_xor(sm, off, 64);
        float mean = sm * (1.0f/128.0f);
        float vs = 0.f;
#pragma unroll
        for (int dt = 0; dt < 8; ++dt) { float d = tmp[dt] - mean; vs = fmaf(d, d, vs); }
#pragma unroll
        for (int off = 1; off < 16; off <<= 1) vs += __shfl_xor(vs, off, 64);
        float inv = 1.f / (sqrtf(vs * (1.0f/128.0f)) + 1e-3f);
        bool keep = (sm != 0.f);
#pragma unroll
        for (int dt = 0; dt < 8; ++dt)
          z3b[gb + dt*16 + lm] = f2b(keep ? (tmp[dt]-mean)*inv : 0.f);
      }
    }
    return;
  }

  // ---- score phase ----
  // x4 -> Y, read back as A-frags (xf persists through both head projections)
#pragma unroll
  for (int reg = 0; reg < 4; ++reg) {
    int r = r0 + reg;
#pragma unroll
    for (int dt = 0; dt < 8; ++dt)
      *(us*)(Y + r*256 + ((2*(dt*16 + lm)) ^ ((r & 7) << 4))) = f2b(x4[dt][reg]);
  }
  s8v xf[4];
#pragma unroll
  for (int ks = 0; ks < 4; ++ks)
    xf[ks] = *(const s8v*)(Y + ar*256 + ((ks*64 + lh*16) ^ ((ar & 7) << 4)));
  // proj head0: xh0 -> Y
  __syncthreads();
  for (int qq = t; qq < 2048; qq += 640) {
    int row = qq >> 4, colb = (qq & 15) << 4;
    s8v v = *(const s8v*)(WcsT + (size_t)row*128 + (colb >> 1));
    char* dst = row < 80 ? W0 : W1;
    int r2 = row < 80 ? row : row - 80;
    *(s8v*)(dst + r2*256 + (colb ^ ((row & 7) << 4))) = v;
  }
  __syncthreads();
#pragma unroll
  for (int dt = 0; dt < 8; ++dt) {
    int row = dt*16 + lm;
    const char* base = dt < 5 ? W0 : W1;
    int r2 = dt < 5 ? row : row - 80;
    f4v acc = {0.f,0.f,0.f,0.f};
#pragma unroll
    for (int ks = 0; ks < 4; ++ks) {
      s8v wf = *(const s8v*)(base + r2*256 + ((ks*64 + lh*16) ^ ((row & 7) << 4)));
      acc = MFMA(xf[ks], wf, acc);
    }
#pragma unroll
    for (int reg = 0; reg < 4; ++reg) {
      int r = r0 + reg;
      *(us*)(Y + r*256 + ((2*(dt*16 + lm)) ^ ((r & 7) << 4))) = f2b(acc[reg]);
    }
  }
  // proj head1: result held in regs, then written to X after weights are dead
  __syncthreads();
  for (int qq = t; qq < 2048; qq += 640) {
    int row = qq >> 4, colb = (qq & 15) << 4;
    s8v v = *(const s8v*)(WcsT + 16384 + (size_t)row*128 + (colb >> 1));
    char* dst = row < 80 ? W0 : W1;
    int r2 = row < 80 ? row : row - 80;
    *(s8v*)(dst + r2*256 + (colb ^ ((row & 7) << 4))) = v;
  }
  __syncthreads();
  f4v ph[8];
#pragma unroll
  for (int dt = 0; dt < 8; ++dt) {
    int row = dt*16 + lm;
    const char* base = dt < 5 ? W0 : W1;
    int r2 = dt < 5 ? row : row - 80;
    f4v acc = {0.f,0.f,0.f,0.f};
#pragma unroll
    for (int ks = 0; ks < 4; ++ks) {
      s8v wf = *(const s8v*)(base + r2*256 + ((ks*64 + lh*16) ^ ((row & 7) << 4)));
      acc = MFMA(xf[ks], wf, acc);
    }
    ph[dt] = acc;
  }
  __syncthreads();
#pragma unroll
  for (int reg = 0; reg < 4; ++reg) {
    int r = r0 + reg;
#pragma unroll
    for (int dt = 0; dt < 8; ++dt)
      *(us*)(X + r*256 + ((2*(dt*16 + lm)) ^ ((r & 7) << 4))) = f2b(ph[dt][reg]);
  }
  __syncthreads();
  // G: group g computes head g. head0: A=Y0,B=Y1; head1: A=X0,B=X1.
  const char* Ab = g ? lds           : (lds + 20480);
  const char* Bb = g ? (lds + 40960) : (lds + 61440);
  s8v af[4];
#pragma unroll
  for (int ks = 0; ks < 4; ++ks)
    af[ks] = *(const s8v*)(Ab + ar*256 + ((ks*64 + lh*16) ^ ((ar & 7) << 4)));
  float loc = 0.f;
#pragma unroll
  for (int nt = 0; nt < 5; ++nt) {
    f4v acc = {0.f,0.f,0.f,0.f};
#pragma unroll
    for (int ks = 0; ks < 4; ++ks) {
      int br = nt*16 + lm;
      s8v bf = *(const s8v*)(Bb + br*256 + ((ks*64 + lh*16) ^ ((br & 7) << 4)));
      acc = MFMA(af[ks], bf, acc);
    }
#pragma unroll
    for (int reg = 0; reg < 4; ++reg) loc += fmaxf(acc[reg]*isq, 0.f);
  }
#pragma unroll
  for (int off = 1; off < 64; off <<= 1) loc += __shfl_xor(loc, off, 64);
  __syncthreads();
  float* red = (float*)(lds + 20480);
  if ((t & 63) == 0) red[t >> 6] = loc;
  __syncthreads();
  if (t == 0) {
    float s0 = red[0]+red[1]+red[2]+red[3]+red[4];
    float s1 = red[5]+red[6]+red[7]+red[8]+red[9];
    float val = (s0*Wcs2[0] + s1*Wcs2[1]) / (xsg[i]*xsg[j]);
    outg[i*SS + j] = val;
    outg[j*SS + i] = val;
  }
}

extern "C" void kernel_launch(void* const* d_in, const int* in_sizes, int n_in,
                              void* d_out, int out_size, void* d_ws, size_t ws_size,
                              hipStream_t stream)
{
  (void)in_sizes; (void)n_in; (void)out_size; (void)ws_size;
  const float* x     = (const float*)d_in[0];
  const float* xs    = (const float*)d_in[1];
  const float* W1    = (const float*)d_in[2];
  const float* W2    = (const float*)d_in[3];
  const float* W3    = (const float*)d_in[4];
  const float* Wq_s  = (const float*)d_in[5];
  const float* Wk_s  = (const float*)d_in[6];
  const float* Wv_s  = (const float*)d_in[7];
  const float* Wh_s  = (const float*)d_in[8];
  const float* Wfc_e = (const float*)d_in[9];
  const float* Wq_c  = (const float*)d_in[10];
  const float* Wk_c  = (const float*)d_in[11];
  const float* Wv_c  = (const float*)d_in[12];
  const float* Wh_c  = (const float*)d_in[13];
  const float* Wfc_d = (const float*)d_in[14];
  const float* Wcs   = (const float*)d_in[15];
  const float* Wcs2  = (const float*)d_in[16];
  float* out = (float*)d_out;

  char* w = (char*)d_ws;
  us* h1b    = (us*)w;     w += (size_t)3840*512*2;
  us* h2b    = (us*)w;     w += (size_t)3840*256*2;
  float* hb  = (float*)w;  w += (size_t)3840*128*4;
  us* zb16   = (us*)w;     w += (size_t)3840*128*2;
  us* z3b    = (us*)w;     w += (size_t)3840*128*2;
  float* e2p = (float*)w;  w += (size_t)3840*128*4;
  us* Qb     = (us*)w;     w += (size_t)3840*256*2;
  us* Kb     = (us*)w;     w += (size_t)3840*256*2;
  us* VT     = (us*)w;     w += (size_t)48*256*80*2;
  us* WhTs   = (us*)w;     w += 128*256*2;
  us* WfcTe  = (us*)w;     w += 128*128*2;
  us* WhTc   = (us*)w;     w += 128*256*2;
  us* WfcTd  = (us*)w;     w += 128*128*2;
  us* WcsT   = (us*)w;     w += 256*128*2;

  hipLaunchKernelGGL(wprep_k, dim3(512), dim3(256), 0, stream,
                     Wh_s, Wfc_e, Wh_c, Wfc_d, Wcs, WhTs, WfcTe, WhTc, WfcTd, WcsT);
  // MLP: h = gelu(gelu(gelu(x@W1)@W2)@W3)
  hipLaunchKernelGGL((mgemm_k<0,0>), dim3(8,60), dim3(256), 0, stream,
                     (const void*)x, W1, (void*)h1b, 512, 512);
  hipLaunchKernelGGL((mgemm_k<1,0>), dim3(4,60), dim3(256), 0, stream,
                     (const void*)h1b, W2, (void*)h2b, 256, 512);
  hipLaunchKernelGGL((mgemm_k<1,1>), dim3(2,60), dim3(256), 0, stream,
                     (const void*)h2b, W3, (void*)hb, 128, 256);
  hipLaunchKernelGGL(norm_k, dim3(3840), dim3(64), 0, stream, hb, zb16);
  // encoder QKV
  hipLaunchKernelGGL(qkv_k, dim3(12,60), dim3(256), 0, stream,
                     zb16, Wq_s, Wk_s, Wv_s, Qb, Kb, VT);
  // encoder block -> e2p (permuted f32), z3b (bf16)
  hipLaunchKernelGGL((encdec_k<0>), dim3(48), dim3(640), 0, stream,
                     Qb, Kb, VT, hb, WhTs, WfcTe, WcsT, Wcs2, xs,
                     e2p, z3b, (float*)nullptr);
  // decoder QKV
  hipLaunchKernelGGL(qkv_k, dim3(12,60), dim3(256), 0, stream,
                     z3b, Wq_c, Wk_c, Wv_c, Qb, Kb, VT);
  // pair decoder + symmetric score
  hipLaunchKernelGGL((encdec_k<1>), dim3(1176), dim3(640), 0, stream,
                     Qb, Kb, VT, e2p, WhTc, WfcTd, WcsT, Wcs2, xs,
                     (float*)nullptr, (us*)nullptr, out);
}